// Round 1
// 161.247 us; speedup vs baseline: 1.1574x; 1.1574x over previous
//
#include <hip/hip_runtime.h>
#include <math.h>

#define B_ 512
#define T_ 256
#define I_ 7
#define H_ 64
#define L_ 16
#define NCH_ (T_ / L_)
#define L2E 1.44269504089f
#define GUARD2 (-21.64f)

typedef short bf16x8 __attribute__((ext_vector_type(8)));
typedef float f32x4 __attribute__((ext_vector_type(4)));

__device__ __forceinline__ unsigned short f2bf(float f) {
  unsigned u = __float_as_uint(f);
  u += 0x7fff + ((u >> 16) & 1);          // RNE
  return (unsigned short)(u >> 16);
}
__device__ __forceinline__ float ex2(float x) { return __builtin_amdgcn_exp2f(x); }
__device__ __forceinline__ float lg2(float x) { return __builtin_amdgcn_logf(x); }
// log2(sigmoid(a)) given a already scaled by log2e
__device__ __forceinline__ float logsig2(float a2) {
  return (a2 < GUARD2) ? a2 : -lg2(1.f + ex2(-a2));
}
__device__ __forceinline__ float sig2(float a2) {
  return __fdividef(1.f, 1.f + ex2(-a2));
}

// Wave-specialized chunkwise mLSTM. 512 threads = 8 waves per batch element.
// Waves 0-3 (consumer): P2 (S, C0 snapshot, C decay+update) + P3 (Num, h) for chunk j.
// Waves 4-7 (producer): gate roles q|ikf|vo|f/Sq computing chunk j+1 into the other
// LDS buffer, split across the two barriers (t 0..7 / 8..15). Wave 7 also runs the
// exact fp32 n-scan for chunk j in the P2 region. All gate tensors double-buffered.
// Gate math in base-2 (weights pre-scaled by log2e) -> bare v_exp/v_log.
// Barriers: every wave executes exactly 1 (B0) + 32 (loop) + 1 (final) = 34.
__global__ __launch_bounds__(512, 4) void mlstm_ws(
    const float* __restrict__ x,
    const float* __restrict__ Cin,
    const float* __restrict__ nin,
    const float* __restrict__ Wq, const float* __restrict__ bq,
    const float* __restrict__ Wk, const float* __restrict__ bk,
    const float* __restrict__ Wv, const float* __restrict__ bv,
    const float* __restrict__ Wi, const float* __restrict__ bi,
    const float* __restrict__ Wf, const float* __restrict__ bf,
    const float* __restrict__ Wo, const float* __restrict__ bo,
    float* __restrict__ hout, float* __restrict__ Cout, float* __restrict__ nout)
{
  const int b    = blockIdx.x;
  const int tid  = threadIdx.x;
  const int lane = tid & 63;
  const int w    = __builtin_amdgcn_readfirstlane(tid >> 6);  // wave 0..7
  const int quad = lane >> 4;
  const int sl   = lane & 15;

  // double-buffered gate tensors (chunk c lives in buffer c&1)
  __shared__ __align__(16) unsigned short sQt[2][L_][72];     // q~ [t][c]
  __shared__ __align__(16) unsigned short sKt[2][L_][72];     // k~ [s][c]
  __shared__ __align__(16) unsigned short sVT[2][H_][56];     // v  [r][s] (s 16..31 zero)
  __shared__ __align__(16) unsigned short sKhatT[2][H_][56];  // K^ [c][s] (s 16..31 zero)
  __shared__ __align__(16) unsigned short sS[L_][56];         // masked S [t][s]
  __shared__ __align__(16) unsigned short sC0[H_][72];        // C0*e^m [r][c]
  __shared__ float sO[2][L_][66];
  __shared__ float sInvDen[2][L_][66];
  __shared__ float sIK[2][L_][H_];
  __shared__ float sFtot[2][H_];
  __shared__ float sEM[2][H_];
  __shared__ float sNv[H_];

  // zero the s>=16 pad regions read by the K=32 MFMAs (both buffers)
  for (int idx = tid; idx < 1024; idx += 512) {
    const int bu = idx >> 9, r = (idx >> 3) & 63, d = idx & 7;
    ((unsigned*)&sVT[0][0][0])[(bu * 64 + r) * 28 + 8 + d]    = 0;
    ((unsigned*)&sKhatT[0][0][0])[(bu * 64 + r) * 28 + 8 + d] = 0;
  }
  if (tid < 128) {
    const int t = tid >> 3, d = tid & 7;
    ((unsigned*)&sS[0][0])[t * 28 + 8 + d] = 0;
  }

  const float* __restrict__ xb = x + (size_t)b * T_ * I_;

  if (w < 4) {
    // ================== CONSUMER: waves 0..3 ==================
    f32x4 Cacc[4];
#pragma unroll
    for (int ct = 0; ct < 4; ++ct)
#pragma unroll
      for (int reg = 0; reg < 4; ++reg)
        Cacc[ct][reg] =
            Cin[(size_t)b * H_ * H_ + (size_t)(16 * w + 4 * quad + reg) * H_ + 16 * ct + sl];
    __syncthreads();  // B0
    for (int j = 0; j < NCH_; ++j) {
      const int p = j & 1;
      // ---- P2: S, C0 snapshot, C decay+update ----
      const bf16x8 aQ0 = *(const bf16x8*)&sQt[p][sl][8 * quad];
      const bf16x8 aQ1 = *(const bf16x8*)&sQt[p][sl][32 + 8 * quad];
      const bf16x8 bK0 = *(const bf16x8*)&sKt[p][sl][8 * quad];
      const bf16x8 bK1 = *(const bf16x8*)&sKt[p][sl][32 + 8 * quad];
      f32x4 S = {0.f, 0.f, 0.f, 0.f};
      S = __builtin_amdgcn_mfma_f32_16x16x32_bf16(aQ0, bK0, S, 0, 0, 0);
      S = __builtin_amdgcn_mfma_f32_16x16x32_bf16(aQ1, bK1, S, 0, 0, 0);
      {  // masked row write (reg == w): D row = 4*quad+reg, col = sl
        const int t = 4 * quad + w;
        const float val = (sl <= t) ? S[w] : 0.f;
        sS[t][sl] = f2bf(val);
      }
      const bf16x8 aV = *(const bf16x8*)&sVT[p][sl + 16 * w][8 * quad];
#pragma unroll
      for (int ct = 0; ct < 4; ++ct) {
        const float em = sEM[p][16 * ct + sl];
        const float ft = sFtot[p][16 * ct + sl];
#pragma unroll
        for (int reg = 0; reg < 4; ++reg)
          sC0[16 * w + 4 * quad + reg][16 * ct + sl] = f2bf(Cacc[ct][reg] * em);
        Cacc[ct] *= ft;
        const bf16x8 bH = *(const bf16x8*)&sKhatT[p][sl + 16 * ct][8 * quad];
        Cacc[ct] = __builtin_amdgcn_mfma_f32_16x16x32_bf16(aV, bH, Cacc[ct], 0, 0, 0);
      }
      __syncthreads();  // B1
      // ---- P3: Num + h ----
      const bf16x8 bC0a = *(const bf16x8*)&sC0[sl + 16 * w][8 * quad];
      const bf16x8 bC0b = *(const bf16x8*)&sC0[sl + 16 * w][32 + 8 * quad];
      f32x4 Num = {0.f, 0.f, 0.f, 0.f};
      Num = __builtin_amdgcn_mfma_f32_16x16x32_bf16(aQ0, bC0a, Num, 0, 0, 0);
      Num = __builtin_amdgcn_mfma_f32_16x16x32_bf16(aQ1, bC0b, Num, 0, 0, 0);
      const bf16x8 aS = *(const bf16x8*)&sS[sl][8 * quad];
      Num = __builtin_amdgcn_mfma_f32_16x16x32_bf16(aS, aV, Num, 0, 0, 0);
#pragma unroll
      for (int reg = 0; reg < 4; ++reg) {
        const int t = 4 * quad + reg;
        const int r = sl + 16 * w;
        const float o   = sO[p][t][r];
        const float idn = sInvDen[p][t][r];
        const float y = Num[reg] * idn;
        const float e = ex2(y * 2.88539008178f);      // e^{2y}
        const float th = 1.f - __fdividef(2.f, e + 1.f);
        hout[(size_t)b * T_ * H_ + (size_t)(j * L_ + t) * H_ + r] = o * th;
      }
      __syncthreads();  // B2
    }
    // epilogue: C
#pragma unroll
    for (int ct = 0; ct < 4; ++ct)
#pragma unroll
      for (int reg = 0; reg < 4; ++reg)
        Cout[(size_t)b * H_ * H_ + (size_t)(16 * w + 4 * quad + reg) * H_ + 16 * ct + sl] =
            Cacc[ct][reg];
  } else if (w == 4) {
    // ================== PRODUCER role 0: q (+f for clf) ==================
    float wq[7], wf[7];
#pragma unroll
    for (int jj = 0; jj < 7; ++jj) {
      wq[jj] = Wq[lane * 7 + jj];
      wf[jj] = Wf[lane * 7 + jj] * L2E;
    }
    const float bQ = bq[lane], bF2 = bf[lane] * L2E;
    {  // prologue: chunk 0, full
      float qp[16], cf[16];
#pragma unroll
      for (int t = 0; t < L_; ++t) {
        float xs[7];
#pragma unroll
        for (int jj = 0; jj < 7; ++jj) xs[jj] = xb[t * 7 + jj];
        float fp = bF2, qq = bQ;
#pragma unroll
        for (int jj = 0; jj < 7; ++jj) { fp = fmaf(xs[jj], wf[jj], fp); qq = fmaf(xs[jj], wq[jj], qq); }
        cf[t] = logsig2(fp);
        qp[t] = qq;
      }
#pragma unroll
      for (int t = 1; t < L_; ++t) cf[t] += cf[t - 1];
      const float m0 = cf[7];
#pragma unroll
      for (int t = 0; t < L_; ++t) sQt[0][t][lane] = f2bf(qp[t] * ex2(cf[t] - m0));
    }
    __syncthreads();  // B0
    float cl[8], m2 = 0.f;
    for (int j = 0; j < NCH_; ++j) {
      const int pn = (j + 1) & 1;
      const float* xc = xb + (size_t)(j + 1) * L_ * I_;
      if (j < NCH_ - 1) {  // half 1: t 0..7 of chunk j+1
        float qp[8];
#pragma unroll
        for (int t = 0; t < 8; ++t) {
          float xs[7];
#pragma unroll
          for (int jj = 0; jj < 7; ++jj) xs[jj] = xc[t * 7 + jj];
          float fp = bF2, qq = bQ;
#pragma unroll
          for (int jj = 0; jj < 7; ++jj) { fp = fmaf(xs[jj], wf[jj], fp); qq = fmaf(xs[jj], wq[jj], qq); }
          cl[t] = logsig2(fp);
          qp[t] = qq;
        }
#pragma unroll
        for (int t = 1; t < 8; ++t) cl[t] += cl[t - 1];
        m2 = cl[7];
#pragma unroll
        for (int t = 0; t < 8; ++t) sQt[pn][t][lane] = f2bf(qp[t] * ex2(cl[t] - m2));
      }
      __syncthreads();  // B1
      if (j < NCH_ - 1) {  // half 2: t 8..15
        float run = cl[7];
#pragma unroll
        for (int t = 8; t < L_; ++t) {
          float xs[7];
#pragma unroll
          for (int jj = 0; jj < 7; ++jj) xs[jj] = xc[t * 7 + jj];
          float fp = bF2, qq = bQ;
#pragma unroll
          for (int jj = 0; jj < 7; ++jj) { fp = fmaf(xs[jj], wf[jj], fp); qq = fmaf(xs[jj], wq[jj], qq); }
          run += logsig2(fp);
          sQt[pn][t][lane] = f2bf(qq * ex2(run - m2));
        }
      }
      __syncthreads();  // B2
    }
  } else if (w == 5) {
    // ================== PRODUCER role 1: i, k (+f) ==================
    float wi[7], wk[7], wf[7];
#pragma unroll
    for (int jj = 0; jj < 7; ++jj) {
      wi[jj] = Wi[lane * 7 + jj] * L2E;
      wk[jj] = Wk[lane * 7 + jj];
      wf[jj] = Wf[lane * 7 + jj] * L2E;
    }
    const float bI2 = bi[lane] * L2E, bK = bk[lane], bF2 = bf[lane] * L2E;
    float cl[16], ikr[16], m2 = 0.f;
    {  // prologue: chunk 0, full
#pragma unroll
      for (int t = 0; t < L_; ++t) {
        float xs[7];
#pragma unroll
        for (int jj = 0; jj < 7; ++jj) xs[jj] = xb[t * 7 + jj];
        float fp = bF2, ip = bI2, kp = bK;
#pragma unroll
        for (int jj = 0; jj < 7; ++jj) {
          fp = fmaf(xs[jj], wf[jj], fp);
          ip = fmaf(xs[jj], wi[jj], ip);
          kp = fmaf(xs[jj], wk[jj], kp);
        }
        cl[t] = logsig2(fp);
        const float ik = ex2(ip) * kp * 0.125f;
        ikr[t] = ik;
        sIK[0][t][lane] = ik;
      }
#pragma unroll
      for (int t = 1; t < L_; ++t) cl[t] += cl[t - 1];
      const float m0 = cl[7], c15 = cl[15];
#pragma unroll
      for (int t = 0; t < L_; ++t) {
        sKt[0][t][lane]    = f2bf(ikr[t] * ex2(m0 - cl[t]));
        sKhatT[0][lane][t] = f2bf(ikr[t] * ex2(c15 - cl[t]));
      }
    }
    __syncthreads();  // B0
    for (int j = 0; j < NCH_; ++j) {
      const int pn = (j + 1) & 1;
      const float* xc = xb + (size_t)(j + 1) * L_ * I_;
      if (j < NCH_ - 1) {  // half 1: t 0..7
#pragma unroll
        for (int t = 0; t < 8; ++t) {
          float xs[7];
#pragma unroll
          for (int jj = 0; jj < 7; ++jj) xs[jj] = xc[t * 7 + jj];
          float fp = bF2, ip = bI2, kp = bK;
#pragma unroll
          for (int jj = 0; jj < 7; ++jj) {
            fp = fmaf(xs[jj], wf[jj], fp);
            ip = fmaf(xs[jj], wi[jj], ip);
            kp = fmaf(xs[jj], wk[jj], kp);
          }
          cl[t] = logsig2(fp);
          const float ik = ex2(ip) * kp * 0.125f;
          ikr[t] = ik;
          sIK[pn][t][lane] = ik;
        }
#pragma unroll
        for (int t = 1; t < 8; ++t) cl[t] += cl[t - 1];
        m2 = cl[7];
#pragma unroll
        for (int t = 0; t < 8; ++t) sKt[pn][t][lane] = f2bf(ikr[t] * ex2(m2 - cl[t]));
      }
      __syncthreads();  // B1
      if (j < NCH_ - 1) {  // half 2: t 8..15 + all sKhatT
#pragma unroll
        for (int t = 8; t < L_; ++t) {
          float xs[7];
#pragma unroll
          for (int jj = 0; jj < 7; ++jj) xs[jj] = xc[t * 7 + jj];
          float fp = bF2, ip = bI2, kp = bK;
#pragma unroll
          for (int jj = 0; jj < 7; ++jj) {
            fp = fmaf(xs[jj], wf[jj], fp);
            ip = fmaf(xs[jj], wi[jj], ip);
            kp = fmaf(xs[jj], wk[jj], kp);
          }
          cl[t] = cl[t - 1] + logsig2(fp);
          const float ik = ex2(ip) * kp * 0.125f;
          ikr[t] = ik;
          sIK[pn][t][lane] = ik;
          sKt[pn][t][lane] = f2bf(ik * ex2(m2 - cl[t]));
        }
        const float c15 = cl[15];
#pragma unroll
        for (int t = 0; t < L_; ++t)
          sKhatT[pn][lane][t] = f2bf(ikr[t] * ex2(c15 - cl[t]));
      }
      __syncthreads();  // B2
    }
  } else if (w == 6) {
    // ================== PRODUCER role 2: v, o ==================
    float wv[7], wo[7];
#pragma unroll
    for (int jj = 0; jj < 7; ++jj) {
      wv[jj] = Wv[lane * 7 + jj];
      wo[jj] = Wo[lane * 7 + jj] * L2E;
    }
    const float bV = bv[lane], bO2 = bo[lane] * L2E;
    {  // prologue: chunk 0, full
#pragma unroll
      for (int t = 0; t < L_; ++t) {
        float xs[7];
#pragma unroll
        for (int jj = 0; jj < 7; ++jj) xs[jj] = xb[t * 7 + jj];
        float vp = bV, op = bO2;
#pragma unroll
        for (int jj = 0; jj < 7; ++jj) { vp = fmaf(xs[jj], wv[jj], vp); op = fmaf(xs[jj], wo[jj], op); }
        sVT[0][lane][t] = f2bf(vp);
        sO[0][t][lane]  = sig2(op);
      }
    }
    __syncthreads();  // B0
    for (int j = 0; j < NCH_; ++j) {
      const int pn = (j + 1) & 1;
      const float* xc = xb + (size_t)(j + 1) * L_ * I_;
      if (j < NCH_ - 1) {  // half 1
#pragma unroll
        for (int t = 0; t < 8; ++t) {
          float xs[7];
#pragma unroll
          for (int jj = 0; jj < 7; ++jj) xs[jj] = xc[t * 7 + jj];
          float vp = bV, op = bO2;
#pragma unroll
          for (int jj = 0; jj < 7; ++jj) { vp = fmaf(xs[jj], wv[jj], vp); op = fmaf(xs[jj], wo[jj], op); }
          sVT[pn][lane][t] = f2bf(vp);
          sO[pn][t][lane]  = sig2(op);
        }
      }
      __syncthreads();  // B1
      if (j < NCH_ - 1) {  // half 2
#pragma unroll
        for (int t = 8; t < L_; ++t) {
          float xs[7];
#pragma unroll
          for (int jj = 0; jj < 7; ++jj) xs[jj] = xc[t * 7 + jj];
          float vp = bV, op = bO2;
#pragma unroll
          for (int jj = 0; jj < 7; ++jj) { vp = fmaf(xs[jj], wv[jj], vp); op = fmaf(xs[jj], wo[jj], op); }
          sVT[pn][lane][t] = f2bf(vp);
          sO[pn][t][lane]  = sig2(op);
        }
      }
      __syncthreads();  // B2
    }
  } else {
    // ================== PRODUCER role 3: f/Sq + exact n-scan ==================
    float wf[7], wqs[8];
#pragma unroll
    for (int jj = 0; jj < 7; ++jj) wf[jj] = Wf[lane * 7 + jj] * L2E;
#pragma unroll
    for (int jj = 0; jj < 7; ++jj) {
      float s = 0.f;
      for (int r = 0; r < H_; ++r) s += Wq[r * 7 + jj];
      wqs[jj] = s;
    }
    {
      float s = 0.f;
      for (int r = 0; r < H_; ++r) s += bq[r];
      wqs[7] = s;
    }
    const float bF2 = bf[lane] * L2E;
    float nv = nin[(size_t)b * H_ * H_ + lane];
    float fs[16], Sq[16], cl[16];
    {  // prologue: chunk 0, full
#pragma unroll
      for (int t = 0; t < L_; ++t) {
        float xs[7];
#pragma unroll
        for (int jj = 0; jj < 7; ++jj) xs[jj] = xb[t * 7 + jj];
        float fp = bF2;
#pragma unroll
        for (int jj = 0; jj < 7; ++jj) fp = fmaf(xs[jj], wf[jj], fp);
        const float ena = ex2(-fp);
        fs[t] = __fdividef(1.f, 1.f + ena);
        cl[t] = (fp < GUARD2) ? fp : -lg2(1.f + ena);
        float S = wqs[7];
#pragma unroll
        for (int jj = 0; jj < 7; ++jj) S = fmaf(xs[jj], wqs[jj], S);
        Sq[t] = S;
      }
#pragma unroll
      for (int t = 1; t < L_; ++t) cl[t] += cl[t - 1];
      sFtot[0][lane] = ex2(cl[15]);
      sEM[0][lane]   = ex2(cl[7]);
    }
    __syncthreads();  // B0
    for (int j = 0; j < NCH_; ++j) {
      const int p = j & 1, pn = p ^ 1;
      // exact fp32 n-scan for chunk j (fs/Sq hold chunk j's values here)
#pragma unroll
      for (int t = 0; t < L_; ++t) {
        nv = fmaf(fs[t], nv, sIK[p][t][lane]);
        sInvDen[p][t][lane] = __fdividef(1.f, fmaxf(nv * Sq[t], 1.f));
      }
      const float* xc = xb + (size_t)(j + 1) * L_ * I_;
      if (j < NCH_ - 1) {  // half 1 for chunk j+1
#pragma unroll
        for (int t = 0; t < 8; ++t) {
          float xs[7];
#pragma unroll
          for (int jj = 0; jj < 7; ++jj) xs[jj] = xc[t * 7 + jj];
          float fp = bF2;
#pragma unroll
          for (int jj = 0; jj < 7; ++jj) fp = fmaf(xs[jj], wf[jj], fp);
          const float ena = ex2(-fp);
          fs[t] = __fdividef(1.f, 1.f + ena);
          cl[t] = (fp < GUARD2) ? fp : -lg2(1.f + ena);
          float S = wqs[7];
#pragma unroll
          for (int jj = 0; jj < 7; ++jj) S = fmaf(xs[jj], wqs[jj], S);
          Sq[t] = S;
        }
#pragma unroll
        for (int t = 1; t < 8; ++t) cl[t] += cl[t - 1];
      }
      __syncthreads();  // B1
      if (j < NCH_ - 1) {  // half 2 for chunk j+1
#pragma unroll
        for (int t = 8; t < L_; ++t) {
          float xs[7];
#pragma unroll
          for (int jj = 0; jj < 7; ++jj) xs[jj] = xc[t * 7 + jj];
          float fp = bF2;
#pragma unroll
          for (int jj = 0; jj < 7; ++jj) fp = fmaf(xs[jj], wf[jj], fp);
          const float ena = ex2(-fp);
          fs[t] = __fdividef(1.f, 1.f + ena);
          cl[t] = cl[t - 1] + ((fp < GUARD2) ? fp : -lg2(1.f + ena));
          float S = wqs[7];
#pragma unroll
          for (int jj = 0; jj < 7; ++jj) S = fmaf(xs[jj], wqs[jj], S);
          Sq[t] = S;
        }
        sFtot[pn][lane] = ex2(cl[15]);
        sEM[pn][lane]   = ex2(cl[7]);
      }
      __syncthreads();  // B2
    }
    sNv[lane] = nv;
  }

  __syncthreads();  // final: sNv ready
  {
    const float nvv = sNv[lane];
#pragma unroll
    for (int k = 0; k < 8; ++k)
      nout[(size_t)b * H_ * H_ + (size_t)(8 * w + k) * H_ + lane] = nvv;
  }
}

extern "C" void kernel_launch(void* const* d_in, const int* in_sizes, int n_in,
                              void* d_out, int out_size, void* d_ws, size_t ws_size,
                              hipStream_t stream) {
  const float* xp  = (const float*)d_in[0];
  const float* Cp  = (const float*)d_in[1];
  const float* np_ = (const float*)d_in[2];

  const float* W[6];
  const float* Bv[6];
  if (n_in >= 15 && in_sizes[4] == 64) {
    for (int g = 0; g < 6; ++g) {
      W[g]  = (const float*)d_in[3 + 2 * g];
      Bv[g] = (const float*)d_in[4 + 2 * g];
    }
  } else {
    for (int g = 0; g < 6; ++g) {
      W[g]  = (const float*)d_in[3 + g];
      Bv[g] = (const float*)d_in[9 + g];
    }
  }

  float* hout = (float*)d_out;
  float* Cout = hout + (size_t)B_ * T_ * H_;
  float* nout = Cout + (size_t)B_ * H_ * H_;

  mlstm_ws<<<dim3(B_), dim3(512), 0, stream>>>(
      xp, Cp, np_,
      W[0], Bv[0], W[1], Bv[1], W[2], Bv[2],
      W[3], Bv[3], W[4], Bv[4], W[5], Bv[5],
      hout, Cout, nout);
}

// Round 2
// 153.570 us; speedup vs baseline: 1.2152x; 1.0500x over previous
//
#include <hip/hip_runtime.h>
#include <math.h>

#define B_ 512
#define T_ 256
#define I_ 7
#define H_ 64
#define L_ 16
#define NCH_ (T_ / L_)
#define L2E 1.44269504089f
#define GUARD2 (-21.64f)

typedef short bf16x8 __attribute__((ext_vector_type(8)));
typedef short short4v __attribute__((ext_vector_type(4)));
typedef float f32x4 __attribute__((ext_vector_type(4)));
typedef float f32x2 __attribute__((ext_vector_type(2)));

__device__ __forceinline__ unsigned short f2bf(float f) {
  unsigned u = __float_as_uint(f);
  u += 0x7fff + ((u >> 16) & 1);          // RNE
  return (unsigned short)(u >> 16);
}
__device__ __forceinline__ float bf2f(unsigned short u) {
  return __uint_as_float(((unsigned)u) << 16);
}
__device__ __forceinline__ float ex2(float x) { return __builtin_amdgcn_exp2f(x); }
__device__ __forceinline__ float lg2(float x) { return __builtin_amdgcn_logf(x); }
// log2(sigmoid(a)) given a already scaled by log2e
__device__ __forceinline__ float logsig2(float a2) {
  return (a2 < GUARD2) ? a2 : -lg2(1.f + ex2(-a2));
}
__device__ __forceinline__ float sig2(float a2) {
  return __fdividef(1.f, 1.f + ex2(-a2));
}

// ---- per-role work packs (chunk production). All operate on 64 channels = lane. ----
#define V_PACK(BUF, XP) do {                                                  \
  unsigned short vv[16];                                                      \
  _Pragma("unroll") for (int t = 0; t < L_; ++t) {                            \
    float vp = bP;                                                            \
    _Pragma("unroll") for (int jj = 0; jj < 7; ++jj)                          \
      vp = fmaf((XP)[t * 7 + jj], wP[jj], vp);                                \
    vv[t] = f2bf(vp);                                                         \
  }                                                                           \
  _Pragma("unroll") for (int tq = 0; tq < 4; ++tq) {                          \
    short4v pk = {(short)vv[4*tq], (short)vv[4*tq+1],                         \
                  (short)vv[4*tq+2], (short)vv[4*tq+3]};                      \
    *(short4v*)&sVT[BUF][lane][4 * tq] = pk;                                  \
  }                                                                           \
} while (0)

#define O_PACK(BUF, XP) do {                                                  \
  _Pragma("unroll") for (int t = 0; t < L_; ++t) {                            \
    float op = bP;                                                            \
    _Pragma("unroll") for (int jj = 0; jj < 7; ++jj)                          \
      op = fmaf((XP)[t * 7 + jj], wP[jj], op);                                \
    sOpre[BUF][t][lane] = f2bf(op);                                           \
  }                                                                           \
} while (0)

#define IK_PRE(XP) do {                                                       \
  _Pragma("unroll") for (int tt = 0; tt < 8; ++tt) {                          \
    const int t = tb + tt;                                                    \
    float ipv = bI2, kpv = bK;                                                \
    _Pragma("unroll") for (int jj = 0; jj < 7; ++jj) {                        \
      const float xv = (XP)[t * 7 + jj];                                      \
      ipv = fmaf(xv, wi2[jj], ipv);                                           \
      kpv = fmaf(xv, wk[jj], kpv);                                            \
    }                                                                         \
    ip8[tt] = ipv; kp8[tt] = kpv;                                             \
  }                                                                           \
} while (0)

#define IK_EXP(BUF) do {                                                      \
  float lsv[16];                                                              \
  _Pragma("unroll") for (int t = 0; t < 16; ++t) lsv[t] = sLs[BUF][lane][t];  \
  _Pragma("unroll") for (int t = 1; t < 16; ++t) lsv[t] += lsv[t - 1];        \
  const float m2 = lsv[7];                                                    \
  const float scl = ex2(lsv[15] - m2);                                        \
  unsigned short kh[8];                                                       \
  _Pragma("unroll") for (int tt = 0; tt < 8; ++tt) {                          \
    const int t = tb + tt;                                                    \
    const float ik = ex2(ip8[tt]) * kp8[tt] * 0.125f;                         \
    sIK[BUF][t][lane] = ik;                                                   \
    const float u = ik * ex2(m2 - lsv[t]);                                    \
    sKt[BUF][t][lane] = f2bf(u);                                              \
    kh[tt] = f2bf(u * scl);                                                   \
  }                                                                           \
  { short4v p0 = {(short)kh[0], (short)kh[1], (short)kh[2], (short)kh[3]};    \
    short4v p1 = {(short)kh[4], (short)kh[5], (short)kh[6], (short)kh[7]};    \
    *(short4v*)&sKhatT[BUF][lane][tb]     = p0;                               \
    *(short4v*)&sKhatT[BUF][lane][tb + 4] = p1; }                             \
} while (0)

#define F_PACK(BUF, XP) do {                                                  \
  float ls[16];                                                               \
  _Pragma("unroll") for (int t = 0; t < 16; ++t) {                            \
    float fp = bF2;                                                           \
    _Pragma("unroll") for (int jj = 0; jj < 7; ++jj)                          \
      fp = fmaf((XP)[t * 7 + jj], wf2[jj], fp);                               \
    ls[t] = logsig2(fp);                                                      \
  }                                                                           \
  _Pragma("unroll") for (int i2 = 0; i2 < 8; ++i2) {                          \
    f32x2 pr = {ls[2 * i2], ls[2 * i2 + 1]};                                  \
    *(f32x2*)&sLs[BUF][lane][2 * i2] = pr;                                    \
  }                                                                           \
  float c = ls[0];                                                            \
  _Pragma("unroll") for (int t = 1; t < 8; ++t) c += ls[t];                   \
  sEM[BUF][lane] = ex2(c);                                                    \
  _Pragma("unroll") for (int t = 8; t < 16; ++t) c += ls[t];                  \
  sFtot[BUF][lane] = ex2(c);                                                  \
} while (0)

#define Q_PACK(BUF, XP) do {                                                  \
  float qq[16];                                                               \
  _Pragma("unroll") for (int t = 0; t < 16; ++t) {                            \
    float qv = bQ;                                                            \
    _Pragma("unroll") for (int jj = 0; jj < 7; ++jj)                          \
      qv = fmaf((XP)[t * 7 + jj], wq[jj], qv);                                \
    qq[t] = qv;                                                               \
  }                                                                           \
  float lsv[16];                                                              \
  _Pragma("unroll") for (int t = 0; t < 16; ++t) lsv[t] = sLs[BUF][lane][t];  \
  _Pragma("unroll") for (int t = 1; t < 16; ++t) lsv[t] += lsv[t - 1];        \
  const float m2 = lsv[7];                                                    \
  _Pragma("unroll") for (int t = 0; t < 16; ++t)                              \
    sQt[BUF][t][lane] = f2bf(qq[t] * ex2(lsv[t] - m2));                       \
} while (0)

// Wave-specialized chunkwise mLSTM, balanced roles. 512 threads = 8 waves/batch.
// w0-3: consumers (P2: S, C0 snapshot, C update | P3: Num, h); w0 also v-pack,
// w1 also o-pack (bf16 preact; sigmoid in P3). w4/w5: i*k for t 0-7 / 8-15
// (preacts in region A, exp+writes in region B). w6: f-gate ONCE (per-t log2-sigmoid
// staged in sLs; readers re-prefix-sum -> identical fp32 values). w7: Sq + exact
// n-scan (region A), q-pack (region B). sKhatT via scale trick reuses sKt exps.
// Each role executes identical barrier sequence: S0,S1 + 16*(B1,B2) + final = 35.
__global__ __launch_bounds__(512, 4) void mlstm_ws2(
    const float* __restrict__ x,
    const float* __restrict__ Cin,
    const float* __restrict__ nin,
    const float* __restrict__ Wq, const float* __restrict__ bq,
    const float* __restrict__ Wk, const float* __restrict__ bk,
    const float* __restrict__ Wv, const float* __restrict__ bv,
    const float* __restrict__ Wi, const float* __restrict__ bi,
    const float* __restrict__ Wf, const float* __restrict__ bf,
    const float* __restrict__ Wo, const float* __restrict__ bo,
    float* __restrict__ hout, float* __restrict__ Cout, float* __restrict__ nout)
{
  const int b    = blockIdx.x;
  const int tid  = threadIdx.x;
  const int lane = tid & 63;
  const int w    = __builtin_amdgcn_readfirstlane(tid >> 6);  // wave 0..7
  const int quad = lane >> 4;
  const int sl   = lane & 15;

  __shared__ __align__(16) unsigned short sQt[2][L_][72];     // q~ [t][c]
  __shared__ __align__(16) unsigned short sKt[2][L_][72];     // k~ [s][c]
  __shared__ __align__(16) unsigned short sVT[2][H_][40];     // v  [r][s] (s 16..31 zero)
  __shared__ __align__(16) unsigned short sKhatT[2][H_][40];  // K^ [c][s] (s 16..31 zero)
  __shared__ __align__(16) unsigned short sS[L_][40];         // masked S [t][s]
  __shared__ __align__(16) unsigned short sC0[H_][72];        // C0*e^m [r][c]
  __shared__ __align__(16) unsigned short sOpre[2][L_][72];   // o preact (base-2), bf16
  __shared__ float sInvDen[2][L_][66];
  __shared__ float sIK[2][L_][H_];
  __shared__ __align__(16) float sLs[2][H_][18];              // per-t log2(sigmoid(f)) [c][t]
  __shared__ float sFtot[2][H_];
  __shared__ float sEM[2][H_];
  __shared__ float sNv[H_];

  // zero the s>=16 pad regions read by the K=32 MFMAs (both buffers)
  for (int idx = tid; idx < 1024; idx += 512) {
    const int bu = idx >> 9, r = (idx >> 3) & 63, d = idx & 7;
    ((unsigned*)sVT)[(bu * 64 + r) * 20 + 8 + d]    = 0;
    ((unsigned*)sKhatT)[(bu * 64 + r) * 20 + 8 + d] = 0;
  }
  if (tid < 128) {
    const int t = tid >> 3, d = tid & 7;
    ((unsigned*)sS)[t * 20 + 8 + d] = 0;
  }

  const float* __restrict__ xb = x + (size_t)b * T_ * I_;

  if (w < 4) {
    // ================== CONSUMERS (+ v-pack on w0, o-pack on w1) ==================
    float wP[7] = {0, 0, 0, 0, 0, 0, 0};
    float bP = 0.f;
    if (w == 0) {
#pragma unroll
      for (int jj = 0; jj < 7; ++jj) wP[jj] = Wv[lane * 7 + jj];
      bP = bv[lane];
    } else if (w == 1) {
#pragma unroll
      for (int jj = 0; jj < 7; ++jj) wP[jj] = Wo[lane * 7 + jj] * L2E;
      bP = bo[lane] * L2E;
    }
    f32x4 Cacc[4];
#pragma unroll
    for (int ct = 0; ct < 4; ++ct)
#pragma unroll
      for (int reg = 0; reg < 4; ++reg)
        Cacc[ct][reg] =
            Cin[(size_t)b * H_ * H_ + (size_t)(16 * w + 4 * quad + reg) * H_ + 16 * ct + sl];
    if (w == 0) V_PACK(0, xb);
    if (w == 1) O_PACK(0, xb);
    __syncthreads();  // S0
    __syncthreads();  // S1
    for (int j = 0; j < NCH_; ++j) {
      const int p = j & 1, pn = p ^ 1;
      const float* xn = xb + (size_t)(j + 1) * L_ * I_;
      // ---- region A: P2 ----
      const bf16x8 aQ0 = *(const bf16x8*)&sQt[p][sl][8 * quad];
      const bf16x8 aQ1 = *(const bf16x8*)&sQt[p][sl][32 + 8 * quad];
      const bf16x8 bK0 = *(const bf16x8*)&sKt[p][sl][8 * quad];
      const bf16x8 bK1 = *(const bf16x8*)&sKt[p][sl][32 + 8 * quad];
      f32x4 S = {0.f, 0.f, 0.f, 0.f};
      S = __builtin_amdgcn_mfma_f32_16x16x32_bf16(aQ0, bK0, S, 0, 0, 0);
      S = __builtin_amdgcn_mfma_f32_16x16x32_bf16(aQ1, bK1, S, 0, 0, 0);
      {  // masked row write (reg == w): D row = 4*quad+reg, col = sl
        const int t = 4 * quad + w;
        const float val = (sl <= t) ? S[w] : 0.f;
        sS[t][sl] = f2bf(val);
      }
      const bf16x8 aV = *(const bf16x8*)&sVT[p][sl + 16 * w][8 * quad];
#pragma unroll
      for (int ct = 0; ct < 4; ++ct) {
        const float em = sEM[p][16 * ct + sl];
        const float ft = sFtot[p][16 * ct + sl];
#pragma unroll
        for (int reg = 0; reg < 4; ++reg)
          sC0[16 * w + 4 * quad + reg][16 * ct + sl] = f2bf(Cacc[ct][reg] * em);
        Cacc[ct] *= ft;
        const bf16x8 bH = *(const bf16x8*)&sKhatT[p][sl + 16 * ct][8 * quad];
        Cacc[ct] = __builtin_amdgcn_mfma_f32_16x16x32_bf16(aV, bH, Cacc[ct], 0, 0, 0);
      }
      if (w == 0 && j + 1 < NCH_) V_PACK(pn, xn);
      if (w == 1 && j + 1 < NCH_) O_PACK(pn, xn);
      __syncthreads();  // B1
      // ---- region B: P3 ----
      const bf16x8 bC0a = *(const bf16x8*)&sC0[sl + 16 * w][8 * quad];
      const bf16x8 bC0b = *(const bf16x8*)&sC0[sl + 16 * w][32 + 8 * quad];
      f32x4 Num = {0.f, 0.f, 0.f, 0.f};
      Num = __builtin_amdgcn_mfma_f32_16x16x32_bf16(aQ0, bC0a, Num, 0, 0, 0);
      Num = __builtin_amdgcn_mfma_f32_16x16x32_bf16(aQ1, bC0b, Num, 0, 0, 0);
      const bf16x8 aS = *(const bf16x8*)&sS[sl][8 * quad];
      Num = __builtin_amdgcn_mfma_f32_16x16x32_bf16(aS, aV, Num, 0, 0, 0);
#pragma unroll
      for (int reg = 0; reg < 4; ++reg) {
        const int t = 4 * quad + reg;
        const int r = sl + 16 * w;
        const float o   = sig2(bf2f(sOpre[p][t][r]));
        const float idn = sInvDen[p][t][r];
        const float y = Num[reg] * idn;
        const float e = ex2(y * 2.88539008178f);  // e^{2y}
        const float th = 1.f - __fdividef(2.f, e + 1.f);
        hout[(size_t)b * T_ * H_ + (size_t)(j * L_ + t) * H_ + r] = o * th;
      }
      __syncthreads();  // B2
    }
    // epilogue: C
#pragma unroll
    for (int ct = 0; ct < 4; ++ct)
#pragma unroll
      for (int reg = 0; reg < 4; ++reg)
        Cout[(size_t)b * H_ * H_ + (size_t)(16 * w + 4 * quad + reg) * H_ + 16 * ct + sl] =
            Cacc[ct][reg];
  } else if (w == 4 || w == 5) {
    // ================== i*k producer (t-half tb..tb+7) ==================
    const int tb = (w == 4) ? 0 : 8;
    float wi2[7], wk[7];
#pragma unroll
    for (int jj = 0; jj < 7; ++jj) {
      wi2[jj] = Wi[lane * 7 + jj] * L2E;
      wk[jj]  = Wk[lane * 7 + jj];
    }
    const float bI2 = bi[lane] * L2E, bK = bk[lane];
    float ip8[8], kp8[8];
    IK_PRE(xb);       // chunk 0 preacts
    __syncthreads();  // S0
    IK_EXP(0);        // chunk 0 exps (needs sLs[0])
    __syncthreads();  // S1
    for (int j = 0; j < NCH_; ++j) {
      const int pn = (j + 1) & 1;
      const float* xn = xb + (size_t)(j + 1) * L_ * I_;
      if (j + 1 < NCH_) IK_PRE(xn);
      __syncthreads();  // B1
      if (j + 1 < NCH_) IK_EXP(pn);
      __syncthreads();  // B2
    }
  } else if (w == 6) {
    // ================== f producer (computed ONCE) ==================
    float wf2[7];
#pragma unroll
    for (int jj = 0; jj < 7; ++jj) wf2[jj] = Wf[lane * 7 + jj] * L2E;
    const float bF2 = bf[lane] * L2E;
    F_PACK(0, xb);    // chunk 0
    __syncthreads();  // S0
    __syncthreads();  // S1
    for (int j = 0; j < NCH_; ++j) {
      const float* xn = xb + (size_t)(j + 1) * L_ * I_;
      const int pn = (j + 1) & 1;
      if (j + 1 < NCH_) F_PACK(pn, xn);
      __syncthreads();  // B1
      __syncthreads();  // B2
    }
  } else {
    // ================== w7: Sq + exact n-scan | q-pack ==================
    float wq[7], wqs[8];
#pragma unroll
    for (int jj = 0; jj < 7; ++jj) wq[jj] = Wq[lane * 7 + jj];
    const float bQ = bq[lane];
#pragma unroll
    for (int jj = 0; jj < 7; ++jj) {
      float s = 0.f;
      for (int r = 0; r < H_; ++r) s += Wq[r * 7 + jj];
      wqs[jj] = s;
    }
    {
      float s = 0.f;
      for (int r = 0; r < H_; ++r) s += bq[r];
      wqs[7] = s;
    }
    float nv = nin[(size_t)b * H_ * H_ + lane];
    __syncthreads();  // S0
    Q_PACK(0, xb);    // chunk 0 (needs sLs[0])
    __syncthreads();  // S1
    for (int j = 0; j < NCH_; ++j) {
      const int p = j & 1, pn = p ^ 1;
      const float* xc = xb + (size_t)j * L_ * I_;
      const float* xn = xb + (size_t)(j + 1) * L_ * I_;
      // region A: exact fp32 n-scan + invden for chunk j (fs = 2^ls exactly)
#pragma unroll
      for (int t = 0; t < 16; ++t) {
        const float fst = ex2(sLs[p][lane][t]);
        float Sqv = wqs[7];
#pragma unroll
        for (int jj = 0; jj < 7; ++jj) Sqv = fmaf(xc[t * 7 + jj], wqs[jj], Sqv);
        nv = fmaf(fst, nv, sIK[p][t][lane]);
        sInvDen[p][t][lane] = __fdividef(1.f, fmaxf(nv * Sqv, 1.f));
      }
      __syncthreads();  // B1
      if (j + 1 < NCH_) Q_PACK(pn, xn);
      __syncthreads();  // B2
    }
    sNv[lane] = nv;
  }

  __syncthreads();  // final: sNv ready
  {
    const float nvv = sNv[lane];
#pragma unroll
    for (int k = 0; k < 8; ++k)
      nout[(size_t)b * H_ * H_ + (size_t)(8 * w + k) * H_ + lane] = nvv;
  }
}

extern "C" void kernel_launch(void* const* d_in, const int* in_sizes, int n_in,
                              void* d_out, int out_size, void* d_ws, size_t ws_size,
                              hipStream_t stream) {
  const float* xp  = (const float*)d_in[0];
  const float* Cp  = (const float*)d_in[1];
  const float* np_ = (const float*)d_in[2];

  const float* W[6];
  const float* Bv[6];
  if (n_in >= 15 && in_sizes[4] == 64) {
    for (int g = 0; g < 6; ++g) {
      W[g]  = (const float*)d_in[3 + 2 * g];
      Bv[g] = (const float*)d_in[4 + 2 * g];
    }
  } else {
    for (int g = 0; g < 6; ++g) {
      W[g]  = (const float*)d_in[3 + g];
      Bv[g] = (const float*)d_in[9 + g];
    }
  }

  float* hout = (float*)d_out;
  float* Cout = hout + (size_t)B_ * T_ * H_;
  float* nout = Cout + (size_t)B_ * H_ * H_;

  mlstm_ws2<<<dim3(B_), dim3(512), 0, stream>>>(
      xp, Cp, np_,
      W[0], Bv[0], W[1], Bv[1], W[2], Bv[2],
      W[3], Bv[3], W[4], Bv[4], W[5], Bv[5],
      hout, Cout, nout);
}